// Round 7
// baseline (18.212 us; speedup 1.0000x reference)
//
#include <hip/hip_runtime.h>
#include <math.h>

// MorphLayer via max-product identity (exp monotone, exp∘log∘clamp = clamp):
//   exp(max_k(log(max(±x,eps)) + w_k)) = max_k( max(±x,eps) * exp(w_k) )
// Negation identity: max(-v,e)*w = max(-(v*w), e*w); e*w ~ 1e-12 -> init 0.
// R7 structural change: weights OFF the LDS pipe. Prep kernel writes
// exp(weights) to d_ws laid out [FG][KK][8]; main reads them with
// wave-uniform indices -> s_load into SGPRs (scalar pipe), LDS holds only x.

#define BB 16
#define CC 3
#define HH 66
#define WW 66
#define HO 64
#define WO 64
#define FF 32
#define KK 27
#define FPG 4               // filters per block
#define FG (FF / FPG)       // 8 filter groups
#define ROWS 4              // output rows per block (1 per thread)
#define IR (ROWS + 2)       // staged input rows = 6

typedef float f32x2 __attribute__((ext_vector_type(2)));

// ew[fg][k][j]: j in 0..3 -> exp(k1[k][fg*4+j]); j in 4..7 -> exp(k2[k][fg*4+j-4])
__global__ void morph_prep(const float* __restrict__ k1,
                           const float* __restrict__ k2,
                           float* __restrict__ ew) {
    const int i = threadIdx.x + blockIdx.x * blockDim.x;
    if (i < FG * KK * 8) {
        const int fg  = i / (KK * 8);
        const int rem = i - fg * (KK * 8);
        const int k   = rem >> 3;
        const int j   = rem & 7;
        const int f   = fg * FPG + (j & 3);
        const float w = (j < 4) ? k1[k * FF + f] : k2[k * FF + f];
        ew[i] = expf(w);
    }
}

__global__ __launch_bounds__(256, 8)
void morph_main(const float* __restrict__ x,
                const float* __restrict__ ew,
                const float* __restrict__ bias,
                float* __restrict__ out) {
    __shared__ __align__(16) float xs[CC * IR * WW];  // 4752 B, x only

    const int tid = threadIdx.x;
    int bid = blockIdx.x;
    const int fg = bid & (FG - 1); bid >>= 3;  // filter group 0..7
    const int rg = bid & 15;       bid >>= 4;  // row group 0..15
    const int b  = bid;                        // batch
    const int f0 = fg * FPG;
    const int ho0 = rg * ROWS;

    // ---- stage raw x window into LDS ----
    const float* xb = x + (size_t)b * CC * HH * WW;
    for (int i = tid; i < CC * IR * WW; i += 256) {
        const int c   = i / (IR * WW);
        const int rem = i - c * (IR * WW);
        const int row = rem / WW;
        const int col = rem - row * WW;
        xs[i] = xb[(c * HH + ho0 + row) * WW + col];
    }
    __syncthreads();

    const int wo = tid & 63;
    const int r  = tid >> 6;
    const int ho = ho0 + r;

    float m11x = 0.f, m11y = 0.f, m11z = 0.f, m11w = 0.f;
    float m12x = 0.f, m12y = 0.f, m12z = 0.f, m12w = 0.f;
    float m21x = 0.f, m21y = 0.f, m21z = 0.f, m21w = 0.f;
    float m22x = 0.f, m22y = 0.f, m22z = 0.f, m22w = 0.f;

    // wave-uniform weight pointer for this block's filter group:
    // per k: wg[k*4+0]=e1.xy wg[k*4+1]=e1.zw wg[k*4+2]=e2.xy wg[k*4+3]=e2.zw
    const f32x2* wg = (const f32x2*)(ew + fg * (KK * 8));

#define XIDX(k) \
    ((((k) / 9) * IR + r + (((k) % 9) / 3)) * WW + wo + ((k) % 3))

    // one k-pair: 2 LDS b32 (x) + uniform s_loads (weights) + 8 pk_mul + 16 max3
#define PAIR(ka, kb) { \
        const float va = xs[XIDX(ka)]; \
        const float vb = xs[XIDX(kb)]; \
        const f32x2 va2 = {va, va}, vb2 = {vb, vb}; \
        const f32x2 pa0 = va2 * wg[(ka)*4+0]; \
        const f32x2 pa1 = va2 * wg[(ka)*4+1]; \
        const f32x2 qa0 = va2 * wg[(ka)*4+2]; \
        const f32x2 qa1 = va2 * wg[(ka)*4+3]; \
        const f32x2 pb0 = vb2 * wg[(kb)*4+0]; \
        const f32x2 pb1 = vb2 * wg[(kb)*4+1]; \
        const f32x2 qb0 = vb2 * wg[(kb)*4+2]; \
        const f32x2 qb1 = vb2 * wg[(kb)*4+3]; \
        m11x = fmaxf(fmaxf(m11x,  pa0.x),  pb0.x); \
        m11y = fmaxf(fmaxf(m11y,  pa0.y),  pb0.y); \
        m11z = fmaxf(fmaxf(m11z,  pa1.x),  pb1.x); \
        m11w = fmaxf(fmaxf(m11w,  pa1.y),  pb1.y); \
        m12x = fmaxf(fmaxf(m12x,  qa0.x),  qb0.x); \
        m12y = fmaxf(fmaxf(m12y,  qa0.y),  qb0.y); \
        m12z = fmaxf(fmaxf(m12z,  qa1.x),  qb1.x); \
        m12w = fmaxf(fmaxf(m12w,  qa1.y),  qb1.y); \
        m21x = fmaxf(fmaxf(m21x, -pa0.x), -pb0.x); \
        m21y = fmaxf(fmaxf(m21y, -pa0.y), -pb0.y); \
        m21z = fmaxf(fmaxf(m21z, -pa1.x), -pb1.x); \
        m21w = fmaxf(fmaxf(m21w, -pa1.y), -pb1.y); \
        m22x = fmaxf(fmaxf(m22x, -qa0.x), -qb0.x); \
        m22y = fmaxf(fmaxf(m22y, -qa0.y), -qb0.y); \
        m22z = fmaxf(fmaxf(m22z, -qa1.x), -qb1.x); \
        m22w = fmaxf(fmaxf(m22w, -qa1.y), -qb1.y); \
    }

    PAIR(0, 1)   PAIR(2, 3)   PAIR(4, 5)   PAIR(6, 7)
    PAIR(8, 9)   PAIR(10, 11) PAIR(12, 13) PAIR(14, 15)
    PAIR(16, 17) PAIR(18, 19) PAIR(20, 21) PAIR(22, 23)
    PAIR(24, 25)
    {   // tail k = 26
        const float va = xs[XIDX(26)];
        const f32x2 va2 = {va, va};
        const f32x2 p0 = va2 * wg[26*4+0];
        const f32x2 p1 = va2 * wg[26*4+1];
        const f32x2 q0 = va2 * wg[26*4+2];
        const f32x2 q1 = va2 * wg[26*4+3];
        m11x = fmaxf(m11x,  p0.x); m11y = fmaxf(m11y,  p0.y);
        m11z = fmaxf(m11z,  p1.x); m11w = fmaxf(m11w,  p1.y);
        m12x = fmaxf(m12x,  q0.x); m12y = fmaxf(m12y,  q0.y);
        m12z = fmaxf(m12z,  q1.x); m12w = fmaxf(m12w,  q1.y);
        m21x = fmaxf(m21x, -p0.x); m21y = fmaxf(m21y, -p0.y);
        m21z = fmaxf(m21z, -p1.x); m21w = fmaxf(m21w, -p1.y);
        m22x = fmaxf(m22x, -q0.x); m22y = fmaxf(m22y, -q0.y);
        m22z = fmaxf(m22z, -q1.x); m22w = fmaxf(m22w, -q1.y);
    }
#undef PAIR
#undef XIDX

    const size_t obase = ((size_t)b * FF + f0) * (HO * WO) + (size_t)ho * WO + wo;
    out[obase + 0 * HO * WO] = m11x - m12x - m21x + m22x + bias[f0 + 0];
    out[obase + 1 * HO * WO] = m11y - m12y - m21y + m22y + bias[f0 + 1];
    out[obase + 2 * HO * WO] = m11z - m12z - m21z + m22z + bias[f0 + 2];
    out[obase + 3 * HO * WO] = m11w - m12w - m21w + m22w + bias[f0 + 3];
}

extern "C" void kernel_launch(void* const* d_in, const int* in_sizes, int n_in,
                              void* d_out, int out_size, void* d_ws, size_t ws_size,
                              hipStream_t stream) {
    const float* x    = (const float*)d_in[0];
    const float* k1   = (const float*)d_in[1];
    const float* k2   = (const float*)d_in[2];
    const float* bias = (const float*)d_in[3];
    float* out = (float*)d_out;
    float* ew  = (float*)d_ws;   // needs FG*KK*8*4 = 6912 bytes

    morph_prep<<<dim3((FG * KK * 8 + 255) / 256), dim3(256), 0, stream>>>(k1, k2, ew);

    const int nblocks = BB * (HO / ROWS) * FG;  // 16 * 16 * 8 = 2048
    morph_main<<<dim3(nblocks), dim3(256), 0, stream>>>(x, ew, bias, out);
}

// Round 8
// 14.776 us; speedup vs baseline: 1.2326x; 1.2326x over previous
//
#include <hip/hip_runtime.h>
#include <math.h>

// MorphLayer via max-product identity (exp monotone, exp∘log∘clamp = clamp):
//   exp(max_k(log(max(±x,eps)) + w_k)) = max_k( max(±x,eps) * exp(w_k) )
// Negation identity: max(-v,e)*w = max(-(v*w), e*w); e*w ~ 1e-12 -> init 0.
// R8: NO x staging / no x-LDS — each thread loads its taps from global
// (L2-resident input, consecutive blocks share windows). Weights in LDS
// (864 B, b128 reads). VALU body identical to R6 (max3 pairs).

#define BB 16
#define CC 3
#define HH 66
#define WW 66
#define HO 64
#define WO 64
#define FF 32
#define KK 27
#define FPG 4               // filters per block
#define FG (FF / FPG)       // 8 filter groups
#define ROWS 4              // output rows per block (1 per thread)

typedef float f32x2  __attribute__((ext_vector_type(2)));
typedef float f32x2u __attribute__((ext_vector_type(2), aligned(4)));

__global__ __launch_bounds__(256, 8)
void morph_fused(const float* __restrict__ x,
                 const float* __restrict__ k1,
                 const float* __restrict__ k2,
                 const float* __restrict__ bias,
                 float* __restrict__ out) {
    __shared__ __align__(16) float wl[KK * 8];   // [k][e1 x4 | e2 x4], 864 B

    const int tid = threadIdx.x;
    int bid = blockIdx.x;
    const int fg = bid & (FG - 1); bid >>= 3;  // filter group 0..7
    const int rg = bid & 15;       bid >>= 4;  // row group 0..15
    const int b  = bid;                        // batch
    const int f0 = fg * FPG;
    const int ho0 = rg * ROWS;

    // ---- stage exp(weights): [k][e1x4|e2x4] ----
    if (tid < KK * 8) {
        const int k = tid >> 3;
        const int j = tid & 3;
        const int h = (tid >> 2) & 1;
        const float w = h ? k2[k * FF + f0 + j] : k1[k * FF + f0 + j];
        wl[tid] = expf(w);
    }
    __syncthreads();

    const int wo = tid & 63;
    const int r  = tid >> 6;   // one output row per thread
    const int ho = ho0 + r;
    const float* xb = x + (size_t)b * CC * HH * WW;

    float m11x = 0.f, m11y = 0.f, m11z = 0.f, m11w = 0.f;
    float m12x = 0.f, m12y = 0.f, m12z = 0.f, m12w = 0.f;
    float m21x = 0.f, m21y = 0.f, m21z = 0.f, m21w = 0.f;
    float m22x = 0.f, m22y = 0.f, m22z = 0.f, m22w = 0.f;

    const float4* wl4 = (const float4*)wl;

    // row ri (0..8): c = ri/3, di = ri%3; taps k = 3*ri + dj.
    // float2 covers dj=0,1 (cols wo..wo+1), scalar dj=2 (col wo+2 <= 65, in-bounds).
#define LOADROW(ri, v0, v1, v2) { \
        const int base_ = (((ri) / 3) * HH + ho + ((ri) % 3)) * WW + wo; \
        const f32x2 t_ = *(const f32x2u*)(xb + base_); \
        v0 = t_.x; v1 = t_.y; v2 = xb[base_ + 2]; \
    }

    // one tap-pair: 4 b128 weight LDS + 8 pk_mul + 16 max3 (identical to R6)
#define PAIR(va, ka, vb, kb) { \
        const float4 w1a = wl4[(ka)*2],   w2a = wl4[(ka)*2+1]; \
        const float4 w1b = wl4[(kb)*2],   w2b = wl4[(kb)*2+1]; \
        const f32x2 va2 = {va, va}, vb2 = {vb, vb}; \
        f32x2 pa0 = va2 * (f32x2){w1a.x, w1a.y}; \
        f32x2 pa1 = va2 * (f32x2){w1a.z, w1a.w}; \
        f32x2 qa0 = va2 * (f32x2){w2a.x, w2a.y}; \
        f32x2 qa1 = va2 * (f32x2){w2a.z, w2a.w}; \
        f32x2 pb0 = vb2 * (f32x2){w1b.x, w1b.y}; \
        f32x2 pb1 = vb2 * (f32x2){w1b.z, w1b.w}; \
        f32x2 qb0 = vb2 * (f32x2){w2b.x, w2b.y}; \
        f32x2 qb1 = vb2 * (f32x2){w2b.z, w2b.w}; \
        m11x = fmaxf(fmaxf(m11x,  pa0.x),  pb0.x); \
        m11y = fmaxf(fmaxf(m11y,  pa0.y),  pb0.y); \
        m11z = fmaxf(fmaxf(m11z,  pa1.x),  pb1.x); \
        m11w = fmaxf(fmaxf(m11w,  pa1.y),  pb1.y); \
        m12x = fmaxf(fmaxf(m12x,  qa0.x),  qb0.x); \
        m12y = fmaxf(fmaxf(m12y,  qa0.y),  qb0.y); \
        m12z = fmaxf(fmaxf(m12z,  qa1.x),  qb1.x); \
        m12w = fmaxf(fmaxf(m12w,  qa1.y),  qb1.y); \
        m21x = fmaxf(fmaxf(m21x, -pa0.x), -pb0.x); \
        m21y = fmaxf(fmaxf(m21y, -pa0.y), -pb0.y); \
        m21z = fmaxf(fmaxf(m21z, -pa1.x), -pb1.x); \
        m21w = fmaxf(fmaxf(m21w, -pa1.y), -pb1.y); \
        m22x = fmaxf(fmaxf(m22x, -qa0.x), -qb0.x); \
        m22y = fmaxf(fmaxf(m22y, -qa0.y), -qb0.y); \
        m22z = fmaxf(fmaxf(m22z, -qa1.x), -qb1.x); \
        m22w = fmaxf(fmaxf(m22w, -qa1.y), -qb1.y); \
    }

    {
        float xa0, xa1, xa2, xb0, xb1, xb2;
        LOADROW(0, xa0, xa1, xa2)  LOADROW(1, xb0, xb1, xb2)
        PAIR(xa0, 0,  xa1, 1)  PAIR(xa2, 2,  xb0, 3)  PAIR(xb1, 4,  xb2, 5)
        LOADROW(2, xa0, xa1, xa2)  LOADROW(3, xb0, xb1, xb2)
        PAIR(xa0, 6,  xa1, 7)  PAIR(xa2, 8,  xb0, 9)  PAIR(xb1, 10, xb2, 11)
        LOADROW(4, xa0, xa1, xa2)  LOADROW(5, xb0, xb1, xb2)
        PAIR(xa0, 12, xa1, 13) PAIR(xa2, 14, xb0, 15) PAIR(xb1, 16, xb2, 17)
        LOADROW(6, xa0, xa1, xa2)  LOADROW(7, xb0, xb1, xb2)
        PAIR(xa0, 18, xa1, 19) PAIR(xa2, 20, xb0, 21) PAIR(xb1, 22, xb2, 23)
        LOADROW(8, xa0, xa1, xa2)
        PAIR(xa0, 24, xa1, 25)
        {   // tail k = 26, value xa2
            const float4 w1 = wl4[26*2], w2 = wl4[26*2+1];
            const f32x2 va2 = {xa2, xa2};
            f32x2 p0 = va2 * (f32x2){w1.x, w1.y};
            f32x2 p1 = va2 * (f32x2){w1.z, w1.w};
            f32x2 q0 = va2 * (f32x2){w2.x, w2.y};
            f32x2 q1 = va2 * (f32x2){w2.z, w2.w};
            m11x = fmaxf(m11x,  p0.x); m11y = fmaxf(m11y,  p0.y);
            m11z = fmaxf(m11z,  p1.x); m11w = fmaxf(m11w,  p1.y);
            m12x = fmaxf(m12x,  q0.x); m12y = fmaxf(m12y,  q0.y);
            m12z = fmaxf(m12z,  q1.x); m12w = fmaxf(m12w,  q1.y);
            m21x = fmaxf(m21x, -p0.x); m21y = fmaxf(m21y, -p0.y);
            m21z = fmaxf(m21z, -p1.x); m21w = fmaxf(m21w, -p1.y);
            m22x = fmaxf(m22x, -q0.x); m22y = fmaxf(m22y, -q0.y);
            m22z = fmaxf(m22z, -q1.x); m22w = fmaxf(m22w, -q1.y);
        }
    }
#undef PAIR
#undef LOADROW

    const size_t obase = ((size_t)b * FF + f0) * (HO * WO) + (size_t)ho * WO + wo;
    out[obase + 0 * HO * WO] = m11x - m12x - m21x + m22x + bias[f0 + 0];
    out[obase + 1 * HO * WO] = m11y - m12y - m21y + m22y + bias[f0 + 1];
    out[obase + 2 * HO * WO] = m11z - m12z - m21z + m22z + bias[f0 + 2];
    out[obase + 3 * HO * WO] = m11w - m12w - m21w + m22w + bias[f0 + 3];
}

extern "C" void kernel_launch(void* const* d_in, const int* in_sizes, int n_in,
                              void* d_out, int out_size, void* d_ws, size_t ws_size,
                              hipStream_t stream) {
    const float* x    = (const float*)d_in[0];
    const float* k1   = (const float*)d_in[1];
    const float* k2   = (const float*)d_in[2];
    const float* bias = (const float*)d_in[3];
    float* out = (float*)d_out;

    const int nblocks = BB * (HO / ROWS) * FG;  // 16 * 16 * 8 = 2048
    morph_fused<<<dim3(nblocks), dim3(256), 0, stream>>>(x, k1, k2, bias, out);
}

// Round 9
// 14.729 us; speedup vs baseline: 1.2365x; 1.0032x over previous
//
#include <hip/hip_runtime.h>
#include <math.h>

// MorphLayer via max-product identity (exp monotone, exp∘log∘clamp = clamp):
//   exp(max_k(log(max(±x,eps)) + w_k)) = max_k( max(±x,eps) * exp(w_k) )
// Negation identity: max(-v,e)*w = max(-(v*w), e*w); e*w ~ 1e-12 -> init 0.
// R9: STORE-PATTERN test. One wave = one filter x (4 rows x 64 cols) tile;
// lane l -> row l>>4, wo4=(l&15)*4, writes one float4 -> wave store is a
// single contiguous 4 KB span (vs 4x256B @16KB stride in all prior rounds).
// x staged in LDS (padded rows), per-wave weights expf'd into LDS.

#define BB 16
#define CC 3
#define HH 66
#define WW 66
#define HO 64
#define WO 64
#define FF 32
#define KK 27
#define FPB 4               // filters per block (1 per wave)
#define FG (FF / FPB)       // 8 filter groups
#define ROWS 4              // output rows per block
#define IR (ROWS + 2)       // staged input rows = 6
#define LP 68               // padded LDS row length (16B-aligned float4 reads)
#define WSTRIDE 56          // padded per-wave weight block (floats)

typedef float f32x2 __attribute__((ext_vector_type(2)));
typedef float f32x4 __attribute__((ext_vector_type(4)));

__global__ __launch_bounds__(256, 8)
void morph_tile(const float* __restrict__ x,
                const float* __restrict__ k1,
                const float* __restrict__ k2,
                const float* __restrict__ bias,
                float* __restrict__ out) {
    __shared__ __align__(16) float xs[CC * IR * LP];       // 4896 B
    __shared__ __align__(16) float wl[FPB * WSTRIDE];      // [w][k][e1,e2], 896 B

    const int tid = threadIdx.x;
    int bid = blockIdx.x;
    const int fg = bid & (FG - 1); bid >>= 3;   // filter group 0..7
    const int rb = bid & 15;       bid >>= 4;   // row band 0..15 (4 rows each)
    const int b  = bid;                         // batch
    const int f0 = fg * FPB;
    const int ho0 = rb * ROWS;

    // ---- per-wave weights: wl[w*WSTRIDE + k*2 + h] = exp((h?k2:k1)[k][f0+w]) ----
    if (tid < FPB * KK * 2) {
        const int w_  = tid / (KK * 2);
        const int rem = tid - w_ * (KK * 2);
        const int k   = rem >> 1;
        const int h   = rem & 1;
        const float wv = h ? k2[k * FF + f0 + w_] : k1[k * FF + f0 + w_];
        wl[w_ * WSTRIDE + k * 2 + h] = expf(wv);
    }
    // ---- stage x window (rows ho0..ho0+5, all 3 channels), padded rows ----
    const float* xbase = x + (size_t)b * CC * HH * WW;
    for (int i = tid; i < CC * IR * WW; i += 256) {
        const int c   = i / (IR * WW);
        const int rem = i - c * (IR * WW);
        const int row = rem / WW;
        const int col = rem - row * WW;
        xs[(c * IR + row) * LP + col] = xbase[(c * HH + ho0 + row) * WW + col];
    }
    __syncthreads();

    const int w   = tid >> 6;          // wave = filter index within group
    const int l   = tid & 63;
    const int rr  = l >> 4;            // row within band, 0..3
    const int wo4 = (l & 15) * 4;      // first output col, 0..60

    const float* wlw = wl + w * WSTRIDE;
    const int f = f0 + w;

    // 16 accumulator chains: 4 wo x {m11,m12,m21,m22}
    float m11_0 = 0.f, m11_1 = 0.f, m11_2 = 0.f, m11_3 = 0.f;
    float m12_0 = 0.f, m12_1 = 0.f, m12_2 = 0.f, m12_3 = 0.f;
    float m21_0 = 0.f, m21_1 = 0.f, m21_2 = 0.f, m21_3 = 0.f;
    float m22_0 = 0.f, m22_1 = 0.f, m22_2 = 0.f, m22_3 = 0.f;

    // tap k with x values (a,b,c,d) for cols wo4..wo4+3
#define TAP(k, va, vb, vc, vd) { \
        const f32x2 e = *(const f32x2*)(wlw + (k) * 2);  /* e1,e2 (uniform) */ \
        const f32x2 ab = {va, vb}, cd = {vc, vd}; \
        const f32x2 e1 = {e.x, e.x}, e2 = {e.y, e.y}; \
        const f32x2 p1 = ab * e1, q1 = cd * e1; \
        const f32x2 p2 = ab * e2, q2 = cd * e2; \
        m11_0 = fmaxf(m11_0,  p1.x); m11_1 = fmaxf(m11_1,  p1.y); \
        m11_2 = fmaxf(m11_2,  q1.x); m11_3 = fmaxf(m11_3,  q1.y); \
        m12_0 = fmaxf(m12_0,  p2.x); m12_1 = fmaxf(m12_1,  p2.y); \
        m12_2 = fmaxf(m12_2,  q2.x); m12_3 = fmaxf(m12_3,  q2.y); \
        m21_0 = fmaxf(m21_0, -p1.x); m21_1 = fmaxf(m21_1, -p1.y); \
        m21_2 = fmaxf(m21_2, -q1.x); m21_3 = fmaxf(m21_3, -q1.y); \
        m22_0 = fmaxf(m22_0, -p2.x); m22_1 = fmaxf(m22_1, -p2.y); \
        m22_2 = fmaxf(m22_2, -q2.x); m22_3 = fmaxf(m22_3, -q2.y); \
    }

    // row chunk (c,di): 6 cols wo4..wo4+5 -> 3 taps (dj=0,1,2)
#define CHUNK(c, di) { \
        const int base_ = ((c * IR + rr + (di)) * LP + wo4); \
        const f32x4 xq = *(const f32x4*)(xs + base_); \
        const f32x2 xr = *(const f32x2*)(xs + base_ + 4); \
        const float s0 = xq.x, s1 = xq.y, s2 = xq.z, s3 = xq.w; \
        const float s4 = xr.x, s5 = xr.y; \
        TAP((c) * 9 + (di) * 3 + 0, s0, s1, s2, s3) \
        TAP((c) * 9 + (di) * 3 + 1, s1, s2, s3, s4) \
        TAP((c) * 9 + (di) * 3 + 2, s2, s3, s4, s5) \
    }

    CHUNK(0, 0) CHUNK(0, 1) CHUNK(0, 2)
    CHUNK(1, 0) CHUNK(1, 1) CHUNK(1, 2)
    CHUNK(2, 0) CHUNK(2, 1) CHUNK(2, 2)
#undef CHUNK
#undef TAP

    const float bs = bias[f];
    f32x4 res;
    res.x = m11_0 - m12_0 - m21_0 + m22_0 + bs;
    res.y = m11_1 - m12_1 - m21_1 + m22_1 + bs;
    res.z = m11_2 - m12_2 - m21_2 + m22_2 + bs;
    res.w = m11_3 - m12_3 - m21_3 + m22_3 + bs;

    // wave-contiguous store: lane l covers bytes [l*16, l*16+16) of a 4 KB span
    *(f32x4*)(out + (((size_t)b * FF + f) * HO + ho0 + rr) * WO + wo4) = res;
}

extern "C" void kernel_launch(void* const* d_in, const int* in_sizes, int n_in,
                              void* d_out, int out_size, void* d_ws, size_t ws_size,
                              hipStream_t stream) {
    const float* x    = (const float*)d_in[0];
    const float* k1   = (const float*)d_in[1];
    const float* k2   = (const float*)d_in[2];
    const float* bias = (const float*)d_in[3];
    float* out = (float*)d_out;

    const int nblocks = BB * (HO / ROWS) * FG;  // 16 * 16 * 8 = 2048
    morph_tile<<<dim3(nblocks), dim3(256), 0, stream>>>(x, k1, k2, bias, out);
}